// Round 1
// baseline (229.234 us; speedup 1.0000x reference)
//
#include <hip/hip_runtime.h>
#include <hip/hip_bf16.h>
#include <cstdint>
#include <cstddef>

#define B_   2
#define H_   12
#define T_   2048
#define C_   768
#define HD_  64
#define M_   4096  // B_*T_

typedef __attribute__((ext_vector_type(8))) short bf16x8;
typedef __attribute__((ext_vector_type(4))) float fx4;
typedef unsigned short u16;

static __device__ __forceinline__ u16 f2bf(float f){
    union { float f; unsigned int i; } c; c.f = f;
    unsigned int x = c.i;
    return (u16)((x + 0x7fffu + ((x >> 16) & 1u)) >> 16);  // RNE
}

// ---------------- fp32 -> bf16 convert ----------------
__global__ void cvt_f32_bf16(const float* __restrict__ src, u16* __restrict__ dst, int n4){
    int i = blockIdx.x * blockDim.x + threadIdx.x;
    if (i < n4){
        float4 v = ((const float4*)src)[i];
        ushort4 o;
        o.x = f2bf(v.x); o.y = f2bf(v.y); o.z = f2bf(v.z); o.w = f2bf(v.w);
        ((ushort4*)dst)[i] = o;
    }
}

// ---------------- fused QKV GEMM ----------------
// C[m,n] = sum_k X[m,k] * W[n,k] + bias[n]; m = b*T+t, n = h*64+d
// z=0 -> Q [B,H,T,64]; z=1 -> K [B,H,T,64]; z=2 -> V^T [B,H,64,T]
__launch_bounds__(256, 2)
__global__ void gemm_qkv(const u16* __restrict__ xb,
                         const u16* __restrict__ wq, const u16* __restrict__ wk,
                         const u16* __restrict__ wv,
                         const float* __restrict__ bq, const float* __restrict__ bk,
                         const float* __restrict__ bv,
                         u16* __restrict__ qo, u16* __restrict__ ko, u16* __restrict__ vto)
{
    const int tid  = threadIdx.x;
    const int lane = tid & 63, wave = tid >> 6;
    const int l15 = lane & 15, lg = lane >> 4;
    const int m0 = blockIdx.y * 128;
    const int n0 = blockIdx.x * 128;
    const int z  = blockIdx.z;
    const u16* wb     = (z == 0) ? wq : (z == 1 ? wk : wv);
    const float* bias = (z == 0) ? bq : (z == 1 ? bk : bv);

    __shared__ __align__(16) u16 lds_a[128 * 32];
    __shared__ __align__(16) u16 lds_b[128 * 32];

    fx4 acc[4][4];
    #pragma unroll
    for (int i = 0; i < 4; i++)
        #pragma unroll
        for (int j = 0; j < 4; j++) acc[i][j] = (fx4)0.0f;

    const int wm = (wave >> 1) * 64, wn = (wave & 1) * 64;

    for (int kt = 0; kt < C_ / 32; ++kt){
        const int k0 = kt * 32;
        #pragma unroll
        for (int c = 0; c < 2; ++c){
            int unit = c * 256 + tid;              // 16B units
            int row = unit >> 2, col = (unit & 3) * 8;
            const u16* ga = xb + (size_t)(m0 + row) * C_ + k0 + col;
            __builtin_amdgcn_global_load_lds((const __attribute__((address_space(1))) void*)ga,
                (__attribute__((address_space(3))) void*)(lds_a + c * 2048 + wave * 512), 16, 0, 0);
            const u16* gb = wb + (size_t)(n0 + row) * C_ + k0 + col;
            __builtin_amdgcn_global_load_lds((const __attribute__((address_space(1))) void*)gb,
                (__attribute__((address_space(3))) void*)(lds_b + c * 2048 + wave * 512), 16, 0, 0);
        }
        __syncthreads();
        bf16x8 af[4], bfr[4];
        #pragma unroll
        for (int i = 0; i < 4; i++){
            af[i]  = *(const bf16x8*)&lds_a[(wm + i * 16 + l15) * 32 + lg * 8];
            bfr[i] = *(const bf16x8*)&lds_b[(wn + i * 16 + l15) * 32 + lg * 8];
        }
        #pragma unroll
        for (int i = 0; i < 4; i++)
            #pragma unroll
            for (int j = 0; j < 4; j++)
                acc[i][j] = __builtin_amdgcn_mfma_f32_16x16x32_bf16(af[i], bfr[j], acc[i][j], 0, 0, 0);
        __syncthreads();
    }

    #pragma unroll
    for (int i = 0; i < 4; i++){
        #pragma unroll
        for (int j = 0; j < 4; j++){
            #pragma unroll
            for (int r = 0; r < 4; r++){
                int m = m0 + wm + i * 16 + lg * 4 + r;
                int n = n0 + wn + j * 16 + l15;
                float v = acc[i][j][r] + bias[n];
                u16 o = f2bf(v);
                int b = m >> 11, t = m & (T_ - 1);
                int h = n >> 6, d = n & 63;
                if (z == 2){
                    vto[(size_t)((b * H_ + h) * HD_ + d) * T_ + t] = o;
                } else {
                    u16* dst = (z == 0) ? qo : ko;
                    dst[(size_t)((b * H_ + h) * T_ + t) * HD_ + d] = o;
                }
            }
        }
    }
}

// ---------------- output projection GEMM (fp32 out) ----------------
__launch_bounds__(256, 2)
__global__ void gemm_proj(const u16* __restrict__ yb, const u16* __restrict__ wp,
                          const float* __restrict__ bp, float* __restrict__ out)
{
    const int tid  = threadIdx.x;
    const int lane = tid & 63, wave = tid >> 6;
    const int l15 = lane & 15, lg = lane >> 4;
    const int m0 = blockIdx.y * 128;
    const int n0 = blockIdx.x * 128;

    __shared__ __align__(16) u16 lds_a[128 * 32];
    __shared__ __align__(16) u16 lds_b[128 * 32];

    fx4 acc[4][4];
    #pragma unroll
    for (int i = 0; i < 4; i++)
        #pragma unroll
        for (int j = 0; j < 4; j++) acc[i][j] = (fx4)0.0f;

    const int wm = (wave >> 1) * 64, wn = (wave & 1) * 64;

    for (int kt = 0; kt < C_ / 32; ++kt){
        const int k0 = kt * 32;
        #pragma unroll
        for (int c = 0; c < 2; ++c){
            int unit = c * 256 + tid;
            int row = unit >> 2, col = (unit & 3) * 8;
            const u16* ga = yb + (size_t)(m0 + row) * C_ + k0 + col;
            __builtin_amdgcn_global_load_lds((const __attribute__((address_space(1))) void*)ga,
                (__attribute__((address_space(3))) void*)(lds_a + c * 2048 + wave * 512), 16, 0, 0);
            const u16* gb = wp + (size_t)(n0 + row) * C_ + k0 + col;
            __builtin_amdgcn_global_load_lds((const __attribute__((address_space(1))) void*)gb,
                (__attribute__((address_space(3))) void*)(lds_b + c * 2048 + wave * 512), 16, 0, 0);
        }
        __syncthreads();
        bf16x8 af[4], bfr[4];
        #pragma unroll
        for (int i = 0; i < 4; i++){
            af[i]  = *(const bf16x8*)&lds_a[(wm + i * 16 + l15) * 32 + lg * 8];
            bfr[i] = *(const bf16x8*)&lds_b[(wn + i * 16 + l15) * 32 + lg * 8];
        }
        #pragma unroll
        for (int i = 0; i < 4; i++)
            #pragma unroll
            for (int j = 0; j < 4; j++)
                acc[i][j] = __builtin_amdgcn_mfma_f32_16x16x32_bf16(af[i], bfr[j], acc[i][j], 0, 0, 0);
        __syncthreads();
    }

    #pragma unroll
    for (int i = 0; i < 4; i++)
        #pragma unroll
        for (int j = 0; j < 4; j++)
            #pragma unroll
            for (int r = 0; r < 4; r++){
                int m = m0 + wm + i * 16 + lg * 4 + r;
                int n = n0 + wn + j * 16 + l15;
                out[(size_t)m * C_ + n] = acc[i][j][r] + bp[n];
            }
}

// ---------------- flash attention ----------------
// grid: (T/64, B*H); 4 waves/block, wave w owns q-rows [qt0+16w, qt0+16w+16)
__launch_bounds__(256, 2)
__global__ void attn(const u16* __restrict__ q, const u16* __restrict__ kmat,
                     const u16* __restrict__ vt, const float* __restrict__ mask,
                     u16* __restrict__ y)
{
    const int tid = threadIdx.x, lane = tid & 63, w = tid >> 6;
    const int l15 = lane & 15, lg = lane >> 4;
    const int bh = blockIdx.y;
    const int b = bh / H_, h = bh % H_;
    const int qt0 = blockIdx.x * 64;
    const int qbase = qt0 + w * 16;

    __shared__ __align__(16) u16 lds_k[64 * 72];
    __shared__ __align__(16) u16 lds_v[64 * 72];
    __shared__ __align__(16) u16 lds_p[4][16 * 72];

    const size_t bhoff = (size_t)bh * T_ * HD_;

    bf16x8 qf[2];
    {
        const u16* qrow = q + bhoff + (size_t)(qbase + l15) * HD_;
        qf[0] = *(const bf16x8*)(qrow + lg * 8);
        qf[1] = *(const bf16x8*)(qrow + 32 + lg * 8);
    }

    fx4 oacc[4];
    #pragma unroll
    for (int i = 0; i < 4; i++) oacc[i] = (fx4)0.0f;
    float mrun[4], lrun[4];
    #pragma unroll
    for (int r = 0; r < 4; r++){ mrun[r] = -1e30f; lrun[r] = 0.0f; }

    const int nkt = blockIdx.x + 1;        // causal: only tiles with k <= q
    const float* maskb = mask + (size_t)b * T_ * T_;

    for (int kt = 0; kt < nkt; ++kt){
        const int kbase = kt * 64;
        {   // stage K tile [64 kpos][64 d] and V^T tile [64 d][64 t], pad to 72
            int r = tid >> 2, c0 = (tid & 3) * 16;
            const u16* ksrc = kmat + bhoff + (size_t)(kbase + r) * HD_ + c0;
            *(bf16x8*)&lds_k[r * 72 + c0]     = *(const bf16x8*)(ksrc);
            *(bf16x8*)&lds_k[r * 72 + c0 + 8] = *(const bf16x8*)(ksrc + 8);
            const u16* vsrc = vt + bhoff + (size_t)r * T_ + kbase + c0;   // r = d
            *(bf16x8*)&lds_v[r * 72 + c0]     = *(const bf16x8*)(vsrc);
            *(bf16x8*)&lds_v[r * 72 + c0 + 8] = *(const bf16x8*)(vsrc + 8);
        }
        __syncthreads();

        // S = Q K^T  (per wave: 16 q-rows x 64 k-cols)
        fx4 s[4];
        #pragma unroll
        for (int ct = 0; ct < 4; ct++){
            s[ct] = (fx4)0.0f;
            #pragma unroll
            for (int ks = 0; ks < 2; ks++){
                bf16x8 bfrag = *(const bf16x8*)&lds_k[(ct * 16 + l15) * 72 + ks * 32 + lg * 8];
                s[ct] = __builtin_amdgcn_mfma_f32_16x16x32_bf16(qf[ks], bfrag, s[ct], 0, 0, 0);
            }
        }

        // scale + causal + attn_mask, track row max
        float pmax[4];
        #pragma unroll
        for (int r = 0; r < 4; r++) pmax[r] = -1e30f;
        #pragma unroll
        for (int ct = 0; ct < 4; ct++){
            #pragma unroll
            for (int r = 0; r < 4; r++){
                int qg = qbase + lg * 4 + r;
                int kg = kbase + ct * 16 + l15;
                float sv = s[ct][r] * 0.125f;
                bool ok = (kg <= qg) && (maskb[(size_t)qg * T_ + kg] > 0.0f);
                sv = ok ? sv : -1e30f;
                s[ct][r] = sv;
                pmax[r] = fmaxf(pmax[r], sv);
            }
        }
        #pragma unroll
        for (int off = 1; off < 16; off <<= 1)
            #pragma unroll
            for (int r = 0; r < 4; r++)
                pmax[r] = fmaxf(pmax[r], __shfl_xor(pmax[r], off, 64));

        float al[4], rsum[4];
        #pragma unroll
        for (int r = 0; r < 4; r++){
            float mnew = fmaxf(mrun[r], pmax[r]);
            al[r] = __expf(mrun[r] - mnew);
            mrun[r] = mnew;
            rsum[r] = 0.0f;
        }

        // P = exp(S - m) -> per-wave LDS (re-layout into A-fragment form)
        #pragma unroll
        for (int ct = 0; ct < 4; ct++){
            #pragma unroll
            for (int r = 0; r < 4; r++){
                float p = __expf(s[ct][r] - mrun[r]);
                rsum[r] += p;
                lds_p[w][(lg * 4 + r) * 72 + ct * 16 + l15] = f2bf(p);
            }
        }
        #pragma unroll
        for (int off = 1; off < 16; off <<= 1)
            #pragma unroll
            for (int r = 0; r < 4; r++)
                rsum[r] += __shfl_xor(rsum[r], off, 64);
        #pragma unroll
        for (int r = 0; r < 4; r++) lrun[r] = lrun[r] * al[r] + rsum[r];
        #pragma unroll
        for (int db = 0; db < 4; db++)
            #pragma unroll
            for (int r = 0; r < 4; r++)
                oacc[db][r] *= al[r];

        bf16x8 pa[2];
        pa[0] = *(const bf16x8*)&lds_p[w][l15 * 72 + lg * 8];
        pa[1] = *(const bf16x8*)&lds_p[w][l15 * 72 + 32 + lg * 8];
        #pragma unroll
        for (int db = 0; db < 4; db++){
            #pragma unroll
            for (int ks = 0; ks < 2; ks++){
                bf16x8 vfrag = *(const bf16x8*)&lds_v[(db * 16 + l15) * 72 + ks * 32 + lg * 8];
                oacc[db] = __builtin_amdgcn_mfma_f32_16x16x32_bf16(pa[ks], vfrag, oacc[db], 0, 0, 0);
            }
        }
        __syncthreads();
    }

    // epilogue: y[b, t, h*64+d] bf16
    #pragma unroll
    for (int db = 0; db < 4; db++){
        #pragma unroll
        for (int r = 0; r < 4; r++){
            int qg = qbase + lg * 4 + r;
            int d = db * 16 + l15;
            float v = oacc[db][r] / lrun[r];
            y[(size_t)(b * T_ + qg) * C_ + h * HD_ + d] = f2bf(v);
        }
    }
}

extern "C" void kernel_launch(void* const* d_in, const int* in_sizes, int n_in,
                              void* d_out, int out_size, void* d_ws, size_t ws_size,
                              hipStream_t stream)
{
    const float* x    = (const float*)d_in[0];
    const float* mask = (const float*)d_in[1];
    const float* Wq   = (const float*)d_in[2];
    const float* bq   = (const float*)d_in[3];
    const float* Wk   = (const float*)d_in[4];
    const float* bk   = (const float*)d_in[5];
    const float* Wv   = (const float*)d_in[6];
    const float* bv   = (const float*)d_in[7];
    const float* Wp   = (const float*)d_in[8];
    const float* bp   = (const float*)d_in[9];
    float* out = (float*)d_out;

    u16* xb  = (u16*)d_ws;                       // [4096,768] bf16 (reused as y later)
    u16* wqb = xb  + (size_t)M_ * C_;
    u16* wkb = wqb + (size_t)C_ * C_;
    u16* wvb = wkb + (size_t)C_ * C_;
    u16* wpb = wvb + (size_t)C_ * C_;
    u16* qo  = wpb + (size_t)C_ * C_;            // [B,H,T,64]
    u16* ko  = qo  + (size_t)M_ * C_;            // [B,H,T,64]
    u16* vto = ko  + (size_t)M_ * C_;            // [B,H,64,T]
    u16* yb  = vto + (size_t)M_ * C_;            // [4096,768] bf16

    const int NX4 = M_ * C_ / 4;
    const int NW4 = C_ * C_ / 4;
    cvt_f32_bf16<<<dim3((NX4 + 255) / 256), 256, 0, stream>>>(x,  xb,  NX4);
    cvt_f32_bf16<<<dim3((NW4 + 255) / 256), 256, 0, stream>>>(Wq, wqb, NW4);
    cvt_f32_bf16<<<dim3((NW4 + 255) / 256), 256, 0, stream>>>(Wk, wkb, NW4);
    cvt_f32_bf16<<<dim3((NW4 + 255) / 256), 256, 0, stream>>>(Wv, wvb, NW4);
    cvt_f32_bf16<<<dim3((NW4 + 255) / 256), 256, 0, stream>>>(Wp, wpb, NW4);

    gemm_qkv<<<dim3(C_ / 128, M_ / 128, 3), 256, 0, stream>>>(
        xb, wqb, wkb, wvb, bq, bk, bv, qo, ko, vto);

    attn<<<dim3(T_ / 64, B_ * H_), 256, 0, stream>>>(qo, ko, vto, mask, yb);

    gemm_proj<<<dim3(C_ / 128, M_ / 128), 256, 0, stream>>>(yb, wpb, bp, out);
}

// Round 2
// 148.189 us; speedup vs baseline: 1.5469x; 1.5469x over previous
//
#include <hip/hip_runtime.h>
#include <hip/hip_bf16.h>
#include <cstdint>
#include <cstddef>

#define B_   2
#define H_   12
#define T_   2048
#define C_   768
#define HD_  64
#define M_   4096  // B_*T_
#define NW_  (T_/64)   // 32 mask words per row

typedef __attribute__((ext_vector_type(8))) short bf16x8;
typedef __attribute__((ext_vector_type(4))) float fx4;
typedef __attribute__((ext_vector_type(2))) unsigned long long u64x2;
typedef unsigned short u16;
typedef unsigned long long u64;

static __device__ __forceinline__ u16 f2bf(float f){
    union { float f; unsigned int i; } c; c.f = f;
    unsigned int x = c.i;
    return (u16)((x + 0x7fffu + ((x >> 16) & 1u)) >> 16);  // RNE
}

// ---------------- fp32 -> bf16 converts ----------------
__global__ void cvt_f32_bf16(const float* __restrict__ src, u16* __restrict__ dst, int n4){
    int i = blockIdx.x * blockDim.x + threadIdx.x;
    if (i < n4){
        float4 v = ((const float4*)src)[i];
        ushort4 o;
        o.x = f2bf(v.x); o.y = f2bf(v.y); o.z = f2bf(v.z); o.w = f2bf(v.w);
        ((ushort4*)dst)[i] = o;
    }
}

// 4 weight matrices -> one contiguous bf16 buffer [wq|wk|wv|wp]
__global__ void cvt_w4(const float* __restrict__ wq, const float* __restrict__ wk,
                       const float* __restrict__ wv, const float* __restrict__ wp,
                       u16* __restrict__ dst){
    const float* src = (blockIdx.y == 0) ? wq : (blockIdx.y == 1) ? wk
                     : (blockIdx.y == 2) ? wv : wp;
    int i = blockIdx.x * blockDim.x + threadIdx.x;
    float4 v = ((const float4*)src)[i];
    ushort4 o;
    o.x = f2bf(v.x); o.y = f2bf(v.y); o.z = f2bf(v.z); o.w = f2bf(v.w);
    ((ushort4*)(dst + (size_t)blockIdx.y * C_ * C_))[i] = o;
}

// ---------------- attn_mask -> bitmask ----------------
// bits[(b*T + t)*NW_ + w] bit j = mask[b][0][t][w*64+j] > 0. One wave per word.
__global__ void mask_bits_kernel(const float* __restrict__ mask, u64* __restrict__ bits){
    int wid  = blockIdx.x * (blockDim.x >> 6) + (threadIdx.x >> 6);
    int lane = threadIdx.x & 63;
    float v = mask[(size_t)wid * 64 + lane];
    u64 m = __ballot(v > 0.0f);
    if (lane == 0) bits[wid] = m;
}

// ---------------- fused QKV GEMM ----------------
// C[m,n] = sum_k X[m,k] * W[n,k] + bias[n]; m = b*T+t, n = h*64+d
// z=0 -> Q [B,H,T,64]; z=1 -> K [B,H,T,64]; z=2 -> V^T [B,H,64,T]
__launch_bounds__(256, 2)
__global__ void gemm_qkv(const u16* __restrict__ xb, const u16* __restrict__ wqkv,
                         const float* __restrict__ bq, const float* __restrict__ bk,
                         const float* __restrict__ bv,
                         u16* __restrict__ qo, u16* __restrict__ ko, u16* __restrict__ vto)
{
    const int tid  = threadIdx.x;
    const int lane = tid & 63, wave = tid >> 6;
    const int l15 = lane & 15, lg = lane >> 4;
    const int m0 = blockIdx.y * 128;
    const int n0 = blockIdx.x * 128;
    const int z  = blockIdx.z;
    const u16* wb     = wqkv + (size_t)z * C_ * C_;
    const float* bias = (z == 0) ? bq : (z == 1 ? bk : bv);

    __shared__ __align__(16) u16 lds_a[128 * 32];
    __shared__ __align__(16) u16 lds_b[128 * 32];

    fx4 acc[4][4];
    #pragma unroll
    for (int i = 0; i < 4; i++)
        #pragma unroll
        for (int j = 0; j < 4; j++) acc[i][j] = (fx4)0.0f;

    const int wm = (wave >> 1) * 64, wn = (wave & 1) * 64;

    for (int kt = 0; kt < C_ / 32; ++kt){
        const int k0 = kt * 32;
        #pragma unroll
        for (int c = 0; c < 2; ++c){
            int unit = c * 256 + tid;              // 16B units
            int row = unit >> 2, col = (unit & 3) * 8;
            const u16* ga = xb + (size_t)(m0 + row) * C_ + k0 + col;
            __builtin_amdgcn_global_load_lds((const __attribute__((address_space(1))) void*)ga,
                (__attribute__((address_space(3))) void*)(lds_a + c * 2048 + wave * 512), 16, 0, 0);
            const u16* gb = wb + (size_t)(n0 + row) * C_ + k0 + col;
            __builtin_amdgcn_global_load_lds((const __attribute__((address_space(1))) void*)gb,
                (__attribute__((address_space(3))) void*)(lds_b + c * 2048 + wave * 512), 16, 0, 0);
        }
        __syncthreads();
        bf16x8 af[4], bfr[4];
        #pragma unroll
        for (int i = 0; i < 4; i++){
            af[i]  = *(const bf16x8*)&lds_a[(wm + i * 16 + l15) * 32 + lg * 8];
            bfr[i] = *(const bf16x8*)&lds_b[(wn + i * 16 + l15) * 32 + lg * 8];
        }
        #pragma unroll
        for (int i = 0; i < 4; i++)
            #pragma unroll
            for (int j = 0; j < 4; j++)
                acc[i][j] = __builtin_amdgcn_mfma_f32_16x16x32_bf16(af[i], bfr[j], acc[i][j], 0, 0, 0);
        __syncthreads();
    }

    #pragma unroll
    for (int i = 0; i < 4; i++){
        #pragma unroll
        for (int j = 0; j < 4; j++){
            #pragma unroll
            for (int r = 0; r < 4; r++){
                int m = m0 + wm + i * 16 + lg * 4 + r;
                int n = n0 + wn + j * 16 + l15;
                float v = acc[i][j][r] + bias[n];
                u16 o = f2bf(v);
                int b = m >> 11, t = m & (T_ - 1);
                int h = n >> 6, d = n & 63;
                if (z == 2){
                    vto[(size_t)((b * H_ + h) * HD_ + d) * T_ + t] = o;
                } else {
                    u16* dst = (z == 0) ? qo : ko;
                    dst[(size_t)((b * H_ + h) * T_ + t) * HD_ + d] = o;
                }
            }
        }
    }
}

// ---------------- output projection GEMM (fp32 out) ----------------
__launch_bounds__(256, 2)
__global__ void gemm_proj(const u16* __restrict__ yb, const u16* __restrict__ wp,
                          const float* __restrict__ bp, float* __restrict__ out)
{
    const int tid  = threadIdx.x;
    const int lane = tid & 63, wave = tid >> 6;
    const int l15 = lane & 15, lg = lane >> 4;
    const int m0 = blockIdx.y * 128;
    const int n0 = blockIdx.x * 128;

    __shared__ __align__(16) u16 lds_a[128 * 32];
    __shared__ __align__(16) u16 lds_b[128 * 32];

    fx4 acc[4][4];
    #pragma unroll
    for (int i = 0; i < 4; i++)
        #pragma unroll
        for (int j = 0; j < 4; j++) acc[i][j] = (fx4)0.0f;

    const int wm = (wave >> 1) * 64, wn = (wave & 1) * 64;

    for (int kt = 0; kt < C_ / 32; ++kt){
        const int k0 = kt * 32;
        #pragma unroll
        for (int c = 0; c < 2; ++c){
            int unit = c * 256 + tid;
            int row = unit >> 2, col = (unit & 3) * 8;
            const u16* ga = yb + (size_t)(m0 + row) * C_ + k0 + col;
            __builtin_amdgcn_global_load_lds((const __attribute__((address_space(1))) void*)ga,
                (__attribute__((address_space(3))) void*)(lds_a + c * 2048 + wave * 512), 16, 0, 0);
            const u16* gb = wp + (size_t)(n0 + row) * C_ + k0 + col;
            __builtin_amdgcn_global_load_lds((const __attribute__((address_space(1))) void*)gb,
                (__attribute__((address_space(3))) void*)(lds_b + c * 2048 + wave * 512), 16, 0, 0);
        }
        __syncthreads();
        bf16x8 af[4], bfr[4];
        #pragma unroll
        for (int i = 0; i < 4; i++){
            af[i]  = *(const bf16x8*)&lds_a[(wm + i * 16 + l15) * 32 + lg * 8];
            bfr[i] = *(const bf16x8*)&lds_b[(wn + i * 16 + l15) * 32 + lg * 8];
        }
        #pragma unroll
        for (int i = 0; i < 4; i++)
            #pragma unroll
            for (int j = 0; j < 4; j++)
                acc[i][j] = __builtin_amdgcn_mfma_f32_16x16x32_bf16(af[i], bfr[j], acc[i][j], 0, 0, 0);
        __syncthreads();
    }

    #pragma unroll
    for (int i = 0; i < 4; i++)
        #pragma unroll
        for (int j = 0; j < 4; j++)
            #pragma unroll
            for (int r = 0; r < 4; r++){
                int m = m0 + wm + i * 16 + lg * 4 + r;
                int n = n0 + wn + j * 16 + l15;
                out[(size_t)m * C_ + n] = acc[i][j][r] + bp[n];
            }
}

// ---------------- flash attention, K-tile = 128 ----------------
// grid: 768 blocks 1D; bh = idx%24, qt = 31 - idx/24 (heavy first).
// 4 waves/block, wave w owns q-rows [qt*64 + 16w, +16)
__launch_bounds__(256, 3)
__global__ void attn(const u16* __restrict__ q, const u16* __restrict__ kmat,
                     const u16* __restrict__ vt, const u64* __restrict__ bits,
                     u16* __restrict__ y)
{
    const int tid = threadIdx.x, lane = tid & 63, w = tid >> 6;
    const int l15 = lane & 15, lg = lane >> 4;
    const int bh = blockIdx.x % (B_ * H_);
    const int qt = (T_ / 64 - 1) - blockIdx.x / (B_ * H_);
    const int b = bh / H_, h = bh % H_;
    const int qt0 = qt * 64;
    const int qbase = qt0 + w * 16;
    const float SCL = 0.125f * 1.44269504f;   // 1/sqrt(64) * log2(e)

    __shared__ __align__(16) u16 lds_k[128 * 72];      // [kpos][d] pad 72
    __shared__ __align__(16) u16 lds_v[64 * 136];      // [d][t]  pad 136
    __shared__ __align__(16) u16 lds_p[4][16 * 136];   // per-wave P re-layout

    const size_t bhoff = (size_t)bh * T_ * HD_;

    bf16x8 qf[2];
    {
        const u16* qrow = q + bhoff + (size_t)(qbase + l15) * HD_;
        qf[0] = *(const bf16x8*)(qrow + lg * 8);
        qf[1] = *(const bf16x8*)(qrow + 32 + lg * 8);
    }

    fx4 oacc[4];
    #pragma unroll
    for (int i = 0; i < 4; i++) oacc[i] = (fx4)0.0f;
    float mrun[4], lrun[4];
    #pragma unroll
    for (int r = 0; r < 4; r++){ mrun[r] = -1e30f; lrun[r] = 0.0f; }

    const int nkt = ((qt0 + 63) >> 7) + 1;    // causal tiles of 128

    for (int kt = 0; kt < nkt; ++kt){
        const int kbase = kt * 128;
        {   // stage K [128][64] and V^T [64][128]
            int r = tid >> 1, c0 = (tid & 1) * 32;
            const u16* ksrc = kmat + bhoff + (size_t)(kbase + r) * HD_ + c0;
            #pragma unroll
            for (int u = 0; u < 4; u++)
                *(bf16x8*)&lds_k[r * 72 + c0 + u * 8] = *(const bf16x8*)(ksrc + u * 8);
            int rv = tid >> 2, cv = (tid & 3) * 32;
            const u16* vsrc = vt + bhoff + (size_t)rv * T_ + kbase + cv;
            #pragma unroll
            for (int u = 0; u < 4; u++)
                *(bf16x8*)&lds_v[rv * 136 + cv + u * 8] = *(const bf16x8*)(vsrc + u * 8);
        }
        __syncthreads();

        // S = Q K^T  (16 q-rows x 128 k-cols per wave)
        fx4 s[8];
        #pragma unroll
        for (int ct = 0; ct < 8; ct++){
            s[ct] = (fx4)0.0f;
            #pragma unroll
            for (int ks = 0; ks < 2; ks++){
                bf16x8 kf = *(const bf16x8*)&lds_k[(ct * 16 + l15) * 72 + ks * 32 + lg * 8];
                s[ct] = __builtin_amdgcn_mfma_f32_16x16x32_bf16(qf[ks], kf, s[ct], 0, 0, 0);
            }
        }

        // causal + attn_mask via bitmask; scale into log2 domain; row max
        float pmax[4];
        #pragma unroll
        for (int r = 0; r < 4; r++){
            const int qg = qbase + lg * 4 + r;
            u64x2 raw = *(const u64x2*)&bits[(size_t)(b * T_ + qg) * NW_ + kt * 2];
            int sh0 = qg - kbase, sh1 = qg - kbase - 64;
            u64 vis0 = sh0 < 0 ? 0ull : (sh0 >= 63 ? ~0ull : ((2ull << sh0) - 1ull));
            u64 vis1 = sh1 < 0 ? 0ull : (sh1 >= 63 ? ~0ull : ((2ull << sh1) - 1ull));
            u64 m0 = (raw[0] & vis0) >> l15;
            u64 m1 = (raw[1] & vis1) >> l15;
            float pm = -1e30f;
            #pragma unroll
            for (int ct = 0; ct < 8; ct++){
                u64 mw = (ct < 4) ? m0 : m1;
                unsigned bit = (unsigned)(mw >> ((ct & 3) * 16)) & 1u;
                float sv = s[ct][r] * SCL;
                sv = bit ? sv : -1e30f;
                s[ct][r] = sv;
                pm = fmaxf(pm, sv);
            }
            pmax[r] = pm;
        }
        #pragma unroll
        for (int off = 1; off < 16; off <<= 1)
            #pragma unroll
            for (int r = 0; r < 4; r++)
                pmax[r] = fmaxf(pmax[r], __shfl_xor(pmax[r], off, 64));

        float al[4], rsum[4];
        #pragma unroll
        for (int r = 0; r < 4; r++){
            float mnew = fmaxf(mrun[r], pmax[r]);
            al[r] = __builtin_amdgcn_exp2f(mrun[r] - mnew);
            mrun[r] = mnew;
            rsum[r] = 0.0f;
        }

        // P = exp2(S - m) -> per-wave LDS (A-fragment re-layout)
        #pragma unroll
        for (int ct = 0; ct < 8; ct++)
            #pragma unroll
            for (int r = 0; r < 4; r++){
                float p = __builtin_amdgcn_exp2f(s[ct][r] - mrun[r]);
                rsum[r] += p;
                lds_p[w][(lg * 4 + r) * 136 + ct * 16 + l15] = f2bf(p);
            }
        #pragma unroll
        for (int off = 1; off < 16; off <<= 1)
            #pragma unroll
            for (int r = 0; r < 4; r++)
                rsum[r] += __shfl_xor(rsum[r], off, 64);
        #pragma unroll
        for (int r = 0; r < 4; r++) lrun[r] = lrun[r] * al[r] + rsum[r];
        #pragma unroll
        for (int db = 0; db < 4; db++)
            #pragma unroll
            for (int r = 0; r < 4; r++)
                oacc[db][r] *= al[r];

        bf16x8 pa[4];
        #pragma unroll
        for (int ks = 0; ks < 4; ks++)
            pa[ks] = *(const bf16x8*)&lds_p[w][l15 * 136 + ks * 32 + lg * 8];
        #pragma unroll
        for (int db = 0; db < 4; db++)
            #pragma unroll
            for (int ks = 0; ks < 4; ks++){
                bf16x8 vf = *(const bf16x8*)&lds_v[(db * 16 + l15) * 136 + ks * 32 + lg * 8];
                oacc[db] = __builtin_amdgcn_mfma_f32_16x16x32_bf16(pa[ks], vf, oacc[db], 0, 0, 0);
            }
        __syncthreads();
    }

    // epilogue: y[b, t, h*64+d] bf16
    #pragma unroll
    for (int db = 0; db < 4; db++){
        #pragma unroll
        for (int r = 0; r < 4; r++){
            int qg = qbase + lg * 4 + r;
            int d = db * 16 + l15;
            float v = oacc[db][r] / lrun[r];
            y[(size_t)(b * T_ + qg) * C_ + h * HD_ + d] = f2bf(v);
        }
    }
}

extern "C" void kernel_launch(void* const* d_in, const int* in_sizes, int n_in,
                              void* d_out, int out_size, void* d_ws, size_t ws_size,
                              hipStream_t stream)
{
    const float* x    = (const float*)d_in[0];
    const float* mask = (const float*)d_in[1];
    const float* Wq   = (const float*)d_in[2];
    const float* bq   = (const float*)d_in[3];
    const float* Wk   = (const float*)d_in[4];
    const float* bk   = (const float*)d_in[5];
    const float* Wv   = (const float*)d_in[6];
    const float* bv   = (const float*)d_in[7];
    const float* Wp   = (const float*)d_in[8];
    const float* bp   = (const float*)d_in[9];
    float* out = (float*)d_out;

    char* p = (char*)d_ws;
    u16* xb   = (u16*)p; p += (size_t)M_ * C_ * 2;       // x bf16
    u16* wqkv = (u16*)p; p += (size_t)4 * C_ * C_ * 2;   // wq|wk|wv|wp bf16
    u16* qo   = (u16*)p; p += (size_t)M_ * C_ * 2;       // [B,H,T,64]
    u16* ko   = (u16*)p; p += (size_t)M_ * C_ * 2;       // [B,H,T,64]
    u16* vto  = (u16*)p; p += (size_t)M_ * C_ * 2;       // [B,H,64,T]
    u16* yb   = (u16*)p; p += (size_t)M_ * C_ * 2;       // attn out bf16
    u64* bits = (u64*)p; p += (size_t)B_ * T_ * NW_ * 8; // mask bitset

    const int NX4 = M_ * C_ / 4;
    const int NW4 = C_ * C_ / 4;
    cvt_f32_bf16<<<dim3((NX4 + 255) / 256), 256, 0, stream>>>(x, xb, NX4);
    cvt_w4<<<dim3(NW4 / 256, 4), 256, 0, stream>>>(Wq, Wk, Wv, Wp, wqkv);
    mask_bits_kernel<<<dim3(B_ * T_ * NW_ / 4), 256, 0, stream>>>(mask, bits);

    gemm_qkv<<<dim3(C_ / 128, M_ / 128, 3), 256, 0, stream>>>(
        xb, wqkv, bq, bk, bv, qo, ko, vto);

    attn<<<dim3((T_ / 64) * B_ * H_), 256, 0, stream>>>(qo, ko, vto, bits, yb);

    gemm_proj<<<dim3(C_ / 128, M_ / 128), 256, 0, stream>>>(yb, wqkv + (size_t)3 * C_ * C_, bp, out);
}

// Round 3
// 106.283 us; speedup vs baseline: 2.1568x; 1.3943x over previous
//
#include <hip/hip_runtime.h>
#include <hip/hip_bf16.h>
#include <cstdint>
#include <cstddef>

#define B_   2
#define H_   12
#define T_   2048
#define C_   768
#define HD_  64
#define M_   4096      // B_*T_
#define NW_  (T_/64)   // 32 mask words per row

typedef __attribute__((ext_vector_type(8))) short bf16x8;
typedef __attribute__((ext_vector_type(4))) float fx4;
typedef __attribute__((ext_vector_type(2))) unsigned long long u64x2;
typedef unsigned short u16;
typedef unsigned int   u32;
typedef unsigned long long u64;

static __device__ __forceinline__ u16 f2bf(float f){
    union { float f; unsigned int i; } c; c.f = f;
    unsigned int x = c.i;
    return (u16)((x + 0x7fffu + ((x >> 16) & 1u)) >> 16);  // RNE
}

static __device__ __forceinline__ u32 pack_bf2(float a, float b){
    union { __hip_bfloat162 h; u32 u; } cv;
    cv.h = __float22bfloat162_rn(make_float2(a, b));   // [15:0]=a, [31:16]=b
    return cv.u;
}

// ---------------- fp32 -> bf16 converts ----------------
__global__ void cvt_f32_bf16(const float* __restrict__ src, u16* __restrict__ dst, int n4){
    int i = blockIdx.x * blockDim.x + threadIdx.x;
    if (i < n4){
        float4 v = ((const float4*)src)[i];
        ushort4 o;
        o.x = f2bf(v.x); o.y = f2bf(v.y); o.z = f2bf(v.z); o.w = f2bf(v.w);
        ((ushort4*)dst)[i] = o;
    }
}

__global__ void cvt_w4(const float* __restrict__ wq, const float* __restrict__ wk,
                       const float* __restrict__ wv, const float* __restrict__ wp,
                       u16* __restrict__ dst){
    const float* src = (blockIdx.y == 0) ? wq : (blockIdx.y == 1) ? wk
                     : (blockIdx.y == 2) ? wv : wp;
    int i = blockIdx.x * blockDim.x + threadIdx.x;
    float4 v = ((const float4*)src)[i];
    ushort4 o;
    o.x = f2bf(v.x); o.y = f2bf(v.y); o.z = f2bf(v.z); o.w = f2bf(v.w);
    ((ushort4*)(dst + (size_t)blockIdx.y * C_ * C_))[i] = o;
}

// ---------------- attn_mask -> bitmask ----------------
__global__ void mask_bits_kernel(const float* __restrict__ mask, u64* __restrict__ bits){
    int wid  = blockIdx.x * (blockDim.x >> 6) + (threadIdx.x >> 6);
    int lane = threadIdx.x & 63;
    float v = mask[(size_t)wid * 64 + lane];
    u64 m = __ballot(v > 0.0f);
    if (lane == 0) bits[wid] = m;
}

// ---------------- fused QKV GEMM, BK=64, swizzled LDS ----------------
// z=0 -> Q (scaled by 0.125*log2e) [B,H,T,64]; z=1 -> K [B,H,T,64]; z=2 -> V^T [B,H,64,T]
__launch_bounds__(256, 2)
__global__ void gemm_qkv(const u16* __restrict__ xb, const u16* __restrict__ wqkv,
                         const float* __restrict__ bq, const float* __restrict__ bk,
                         const float* __restrict__ bv,
                         u16* __restrict__ qo, u16* __restrict__ ko, u16* __restrict__ vto)
{
    const int tid  = threadIdx.x;
    const int lane = tid & 63, wave = tid >> 6;
    const int l15 = lane & 15, lg = lane >> 4;
    const int m0 = blockIdx.y * 128;
    const int n0 = blockIdx.x * 128;
    const int z  = blockIdx.z;
    const u16* wb     = wqkv + (size_t)z * C_ * C_;
    const float* bias = (z == 0) ? bq : (z == 1 ? bk : bv);
    const float oscl  = (z == 0) ? 0.1803368801111601f : 1.0f;  // 0.125*log2(e)

    __shared__ __align__(16) u16 lds_a[128 * 64];
    __shared__ __align__(16) u16 lds_b[128 * 64];

    fx4 acc[4][4];
    #pragma unroll
    for (int i = 0; i < 4; i++)
        #pragma unroll
        for (int j = 0; j < 4; j++) acc[i][j] = (fx4)0.0f;

    const int wm = (wave >> 1) * 64, wn = (wave & 1) * 64;
    const int sx = l15 & 7;   // fragment-read swizzle

    for (int kt = 0; kt < C_ / 64; ++kt){
        const int k0 = kt * 64;
        #pragma unroll
        for (int c = 0; c < 4; ++c){
            int unit = c * 256 + tid;              // 16B units, 8 per row
            int row = unit >> 3, col = unit & 7;
            int gcol = (col ^ (row & 7)) * 8;      // pre-swizzled source
            const u16* ga = xb + (size_t)(m0 + row) * C_ + k0 + gcol;
            __builtin_amdgcn_global_load_lds((const __attribute__((address_space(1))) void*)ga,
                (__attribute__((address_space(3))) void*)(lds_a + (c * 256 + wave * 64) * 8), 16, 0, 0);
            const u16* gb = wb + (size_t)(n0 + row) * C_ + k0 + gcol;
            __builtin_amdgcn_global_load_lds((const __attribute__((address_space(1))) void*)gb,
                (__attribute__((address_space(3))) void*)(lds_b + (c * 256 + wave * 64) * 8), 16, 0, 0);
        }
        __syncthreads();
        #pragma unroll
        for (int ks = 0; ks < 2; ++ks){
            bf16x8 af[4], bfr[4];
            #pragma unroll
            for (int i = 0; i < 4; i++){
                af[i]  = *(const bf16x8*)&lds_a[(wm + i * 16 + l15) * 64 + (((4 * ks + lg) ^ sx) * 8)];
                bfr[i] = *(const bf16x8*)&lds_b[(wn + i * 16 + l15) * 64 + (((4 * ks + lg) ^ sx) * 8)];
            }
            #pragma unroll
            for (int i = 0; i < 4; i++)
                #pragma unroll
                for (int j = 0; j < 4; j++)
                    acc[i][j] = __builtin_amdgcn_mfma_f32_16x16x32_bf16(af[i], bfr[j], acc[i][j], 0, 0, 0);
        }
        __syncthreads();
    }

    #pragma unroll
    for (int i = 0; i < 4; i++){
        #pragma unroll
        for (int j = 0; j < 4; j++){
            #pragma unroll
            for (int r = 0; r < 4; r++){
                int m = m0 + wm + i * 16 + lg * 4 + r;
                int n = n0 + wn + j * 16 + l15;
                float v = (acc[i][j][r] + bias[n]) * oscl;
                u16 o = f2bf(v);
                int b = m >> 11, t = m & (T_ - 1);
                int h = n >> 6, d = n & 63;
                if (z == 2){
                    vto[(size_t)((b * H_ + h) * HD_ + d) * T_ + t] = o;
                } else {
                    u16* dst = (z == 0) ? qo : ko;
                    dst[(size_t)((b * H_ + h) * T_ + t) * HD_ + d] = o;
                }
            }
        }
    }
}

// ---------------- output projection GEMM (fp32 out), BK=64 ----------------
__launch_bounds__(256, 2)
__global__ void gemm_proj(const u16* __restrict__ yb, const u16* __restrict__ wp,
                          const float* __restrict__ bp, float* __restrict__ out)
{
    const int tid  = threadIdx.x;
    const int lane = tid & 63, wave = tid >> 6;
    const int l15 = lane & 15, lg = lane >> 4;
    const int m0 = blockIdx.y * 128;
    const int n0 = blockIdx.x * 128;

    __shared__ __align__(16) u16 lds_a[128 * 64];
    __shared__ __align__(16) u16 lds_b[128 * 64];

    fx4 acc[4][4];
    #pragma unroll
    for (int i = 0; i < 4; i++)
        #pragma unroll
        for (int j = 0; j < 4; j++) acc[i][j] = (fx4)0.0f;

    const int wm = (wave >> 1) * 64, wn = (wave & 1) * 64;
    const int sx = l15 & 7;

    for (int kt = 0; kt < C_ / 64; ++kt){
        const int k0 = kt * 64;
        #pragma unroll
        for (int c = 0; c < 4; ++c){
            int unit = c * 256 + tid;
            int row = unit >> 3, col = unit & 7;
            int gcol = (col ^ (row & 7)) * 8;
            const u16* ga = yb + (size_t)(m0 + row) * C_ + k0 + gcol;
            __builtin_amdgcn_global_load_lds((const __attribute__((address_space(1))) void*)ga,
                (__attribute__((address_space(3))) void*)(lds_a + (c * 256 + wave * 64) * 8), 16, 0, 0);
            const u16* gb = wp + (size_t)(n0 + row) * C_ + k0 + gcol;
            __builtin_amdgcn_global_load_lds((const __attribute__((address_space(1))) void*)gb,
                (__attribute__((address_space(3))) void*)(lds_b + (c * 256 + wave * 64) * 8), 16, 0, 0);
        }
        __syncthreads();
        #pragma unroll
        for (int ks = 0; ks < 2; ++ks){
            bf16x8 af[4], bfr[4];
            #pragma unroll
            for (int i = 0; i < 4; i++){
                af[i]  = *(const bf16x8*)&lds_a[(wm + i * 16 + l15) * 64 + (((4 * ks + lg) ^ sx) * 8)];
                bfr[i] = *(const bf16x8*)&lds_b[(wn + i * 16 + l15) * 64 + (((4 * ks + lg) ^ sx) * 8)];
            }
            #pragma unroll
            for (int i = 0; i < 4; i++)
                #pragma unroll
                for (int j = 0; j < 4; j++)
                    acc[i][j] = __builtin_amdgcn_mfma_f32_16x16x32_bf16(af[i], bfr[j], acc[i][j], 0, 0, 0);
        }
        __syncthreads();
    }

    #pragma unroll
    for (int i = 0; i < 4; i++)
        #pragma unroll
        for (int j = 0; j < 4; j++)
            #pragma unroll
            for (int r = 0; r < 4; r++){
                int m = m0 + wm + i * 16 + lg * 4 + r;
                int n = n0 + wn + j * 16 + l15;
                out[(size_t)m * C_ + n] = acc[i][j][r] + bp[n];
            }
}

// ---------------- flash attention: swapped QK^T, in-lane softmax ----------------
// grid: 768 blocks 1D; bh = idx%24, qt = 31 - idx/24 (heavy first).
// 4 waves/block; wave w owns q-rows [qt*64+16w, +16). Lane owns q = qbase + l15.
// Q pre-scaled by 0.125*log2(e) -> all scores in log2 domain.
__launch_bounds__(256, 2)
__global__ void attn(const u16* __restrict__ q, const u16* __restrict__ kmat,
                     const u16* __restrict__ vt, const u64* __restrict__ bits,
                     u16* __restrict__ y)
{
    const int tid = threadIdx.x, lane = tid & 63, w = tid >> 6;
    const int l15 = lane & 15, lg = lane >> 4;
    const int bh = blockIdx.x % (B_ * H_);
    const int qt = (T_ / 64 - 1) - blockIdx.x / (B_ * H_);
    const int b = bh / H_, h = bh % H_;
    const int qt0 = qt * 64;
    const int qbase = qt0 + w * 16;

    __shared__ __align__(16) u16 lds_k[128 * 64];      // [k][d], XOR col16^=(row&7)
    __shared__ __align__(16) u16 lds_v[64 * 128];      // [d][t], XOR
    __shared__ __align__(16) u32 lds_p[4][16 * 68];    // per-wave P, rows of 68 words

    const size_t bhoff = (size_t)bh * T_ * HD_;
    const int sx = l15 & 7;

    bf16x8 qf[2];
    {
        const u16* qrow = q + bhoff + (size_t)(qbase + l15) * HD_;
        qf[0] = *(const bf16x8*)(qrow + lg * 8);
        qf[1] = *(const bf16x8*)(qrow + 32 + lg * 8);
    }

    fx4 oacc[4];
    #pragma unroll
    for (int i = 0; i < 4; i++) oacc[i] = (fx4)0.0f;
    float m_l = -1e30f, l_l = 0.0f;                    // per-lane (q = qbase+l15)

    const int nkt = ((qt0 + 63) >> 7) + 1;             // causal tiles of 128
    const int qg  = qbase + l15;
    const u64* brow = bits + (size_t)(b * T_ + qg) * NW_;

    // staging assignments (per thread): K 4 units, V 4 units
    const int kr0 = tid >> 3,  kc0 = tid & 7;          // + i*32 rows
    const int vr0 = tid >> 4,  vc0 = tid & 15;         // + i*16 rows

    bf16x8 kreg[4], vreg[4];
    {   // prologue: tile 0
        #pragma unroll
        for (int i = 0; i < 4; i++){
            int row = kr0 + i * 32;
            kreg[i] = *(const bf16x8*)(kmat + bhoff + (size_t)row * HD_ + kc0 * 8);
            int rv = vr0 + i * 16;
            vreg[i] = *(const bf16x8*)(vt + bhoff + (size_t)rv * T_ + vc0 * 8);
        }
        #pragma unroll
        for (int i = 0; i < 4; i++){
            int row = kr0 + i * 32;
            *(bf16x8*)&lds_k[row * 64 + ((kc0 ^ (row & 7)) * 8)] = kreg[i];
            int rv = vr0 + i * 16;
            *(bf16x8*)&lds_v[rv * 128 + ((vc0 ^ (rv & 7)) * 8)] = vreg[i];
        }
    }
    __syncthreads();

    for (int kt = 0; kt < nkt; ++kt){
        const int kbase = kt * 128;
        const bool pf = (kt + 1 < nkt);
        if (pf){   // prefetch next tile into regs (hidden under compute)
            const int kb2 = kbase + 128;
            #pragma unroll
            for (int i = 0; i < 4; i++){
                int row = kr0 + i * 32;
                kreg[i] = *(const bf16x8*)(kmat + bhoff + (size_t)(kb2 + row) * HD_ + kc0 * 8);
                int rv = vr0 + i * 16;
                vreg[i] = *(const bf16x8*)(vt + bhoff + (size_t)rv * T_ + kb2 + vc0 * 8);
            }
        }

        // S^T = K Q^T : lane holds S[k = kbase+16ct+4lg+r][q = qbase+l15]
        fx4 s[8];
        #pragma unroll
        for (int ct = 0; ct < 8; ct++){
            s[ct] = (fx4)0.0f;
            #pragma unroll
            for (int ks = 0; ks < 2; ks++){
                bf16x8 kf = *(const bf16x8*)&lds_k[(ct * 16 + l15) * 64 + (((4 * ks + lg) ^ sx) * 8)];
                s[ct] = __builtin_amdgcn_mfma_f32_16x16x32_bf16(kf, qf[ks], s[ct], 0, 0, 0);
            }
        }

        // causal + attn_mask (per-lane row), in-lane max
        u64x2 raw = *(const u64x2*)&brow[kt * 2];
        int sh0 = qg - kbase, sh1 = qg - kbase - 64;
        u64 vis0 = sh0 < 0 ? 0ull : (sh0 >= 63 ? ~0ull : ((2ull << sh0) - 1ull));
        u64 vis1 = sh1 < 0 ? 0ull : (sh1 >= 63 ? ~0ull : ((2ull << sh1) - 1ull));
        u64 ms0 = (raw[0] & vis0) >> (lg * 4);
        u64 ms1 = (raw[1] & vis1) >> (lg * 4);
        float mx = -1e30f;
        #pragma unroll
        for (int ct = 0; ct < 8; ct++){
            u64 msel = (ct < 4) ? ms0 : ms1;
            int base = 16 * (ct & 3);
            #pragma unroll
            for (int r = 0; r < 4; r++){
                u32 bit = (u32)(msel >> (base + r)) & 1u;
                float sv = bit ? s[ct][r] : -1e30f;
                s[ct][r] = sv;
                mx = fmaxf(mx, sv);
            }
        }
        mx = fmaxf(mx, __shfl_xor(mx, 16, 64));
        mx = fmaxf(mx, __shfl_xor(mx, 32, 64));

        float mnew = fmaxf(m_l, mx);
        float al = __builtin_amdgcn_exp2f(m_l - mnew);
        m_l = mnew;

        // P = exp2(S - m), in-lane sum, pack -> per-wave LDS (packed u32 pairs)
        float rs = 0.0f;
        #pragma unroll
        for (int ct = 0; ct < 8; ct++){
            float p0 = __builtin_amdgcn_exp2f(s[ct][0] - mnew);
            float p1 = __builtin_amdgcn_exp2f(s[ct][1] - mnew);
            float p2 = __builtin_amdgcn_exp2f(s[ct][2] - mnew);
            float p3 = __builtin_amdgcn_exp2f(s[ct][3] - mnew);
            rs += (p0 + p1) + (p2 + p3);
            uint2 pk; pk.x = pack_bf2(p0, p1); pk.y = pack_bf2(p2, p3);
            *(uint2*)&lds_p[w][l15 * 68 + 8 * ct + 2 * lg] = pk;
        }
        rs += __shfl_xor(rs, 16, 64);
        rs += __shfl_xor(rs, 32, 64);
        l_l = l_l * al + rs;

        // rescale O: rows of D are q = qbase + lg*4+r -> fetch their al
        #pragma unroll
        for (int r = 0; r < 4; r++){
            float alr = __shfl(al, lg * 4 + r, 64);
            #pragma unroll
            for (int db = 0; db < 4; db++) oacc[db][r] *= alr;
        }

        // PV: A = P (lane holds row q=l15, k=32ks+8lg+j), B = V^T
        #pragma unroll
        for (int ks = 0; ks < 4; ks++){
            bf16x8 paf = *(const bf16x8*)&lds_p[w][l15 * 68 + 16 * ks + 4 * lg];
            #pragma unroll
            for (int db = 0; db < 4; db++){
                bf16x8 vf = *(const bf16x8*)&lds_v[(db * 16 + l15) * 128 + (((4 * ks + lg) ^ sx) * 8)];
                oacc[db] = __builtin_amdgcn_mfma_f32_16x16x32_bf16(paf, vf, oacc[db], 0, 0, 0);
            }
        }

        if (pf){
            __syncthreads();   // all waves done reading tile kt
            #pragma unroll
            for (int i = 0; i < 4; i++){
                int row = kr0 + i * 32;
                *(bf16x8*)&lds_k[row * 64 + ((kc0 ^ (row & 7)) * 8)] = kreg[i];
                int rv = vr0 + i * 16;
                *(bf16x8*)&lds_v[rv * 128 + ((vc0 ^ (rv & 7)) * 8)] = vreg[i];
            }
            __syncthreads();   // tile kt+1 ready
        }
    }

    // epilogue: y[b, t, h*64+d]; O rows q = qbase + lg*4+r, cols d = db*16+l15
    #pragma unroll
    for (int r = 0; r < 4; r++){
        float lr = __shfl(l_l, lg * 4 + r, 64);
        float inv = 1.0f / lr;
        int qrow = qbase + lg * 4 + r;
        #pragma unroll
        for (int db = 0; db < 4; db++){
            int d = db * 16 + l15;
            y[(size_t)(b * T_ + qrow) * C_ + h * HD_ + d] = f2bf(oacc[db][r] * inv);
        }
    }
}

extern "C" void kernel_launch(void* const* d_in, const int* in_sizes, int n_in,
                              void* d_out, int out_size, void* d_ws, size_t ws_size,
                              hipStream_t stream)
{
    const float* x    = (const float*)d_in[0];
    const float* mask = (const float*)d_in[1];
    const float* Wq   = (const float*)d_in[2];
    const float* bq   = (const float*)d_in[3];
    const float* Wk   = (const float*)d_in[4];
    const float* bk   = (const float*)d_in[5];
    const float* Wv   = (const float*)d_in[6];
    const float* bv   = (const float*)d_in[7];
    const float* Wp   = (const float*)d_in[8];
    const float* bp   = (const float*)d_in[9];
    float* out = (float*)d_out;

    char* p = (char*)d_ws;
    u16* xb   = (u16*)p; p += (size_t)M_ * C_ * 2;       // x bf16
    u16* wqkv = (u16*)p; p += (size_t)4 * C_ * C_ * 2;   // wq|wk|wv|wp bf16
    u16* qo   = (u16*)p; p += (size_t)M_ * C_ * 2;       // [B,H,T,64] (pre-scaled)
    u16* ko   = (u16*)p; p += (size_t)M_ * C_ * 2;       // [B,H,T,64]
    u16* vto  = (u16*)p; p += (size_t)M_ * C_ * 2;       // [B,H,64,T]
    u16* yb   = (u16*)p; p += (size_t)M_ * C_ * 2;       // attn out bf16
    u64* bits = (u64*)p; p += (size_t)B_ * T_ * NW_ * 8; // mask bitset

    const int NX4 = M_ * C_ / 4;
    const int NW4 = C_ * C_ / 4;
    cvt_f32_bf16<<<dim3((NX4 + 255) / 256), 256, 0, stream>>>(x, xb, NX4);
    cvt_w4<<<dim3(NW4 / 256, 4), 256, 0, stream>>>(Wq, Wk, Wv, Wp, wqkv);
    mask_bits_kernel<<<dim3(B_ * T_ * NW_ / 4), 256, 0, stream>>>(mask, bits);

    gemm_qkv<<<dim3(C_ / 128, M_ / 128, 3), 256, 0, stream>>>(
        xb, wqkv, bq, bk, bv, qo, ko, vto);

    attn<<<dim3((T_ / 64) * B_ * H_), 256, 0, stream>>>(qo, ko, vto, bits, yb);

    gemm_proj<<<dim3(C_ / 128, M_ / 128), 256, 0, stream>>>(yb, wqkv + (size_t)3 * C_ * C_, bp, out);
}